// Round 20
// baseline (764.073 us; speedup 1.0000x reference)
//
#include <hip/hip_runtime.h>
#include <hip/hip_bf16.h>
#include <math.h>

// ---------------------------------------------------------------------------
// GATv2 x2 + global_add_pool + MLP head.
// xl/xr/h1/EEself as bf16. k_fused: R13-validated MFMA edge kernel, 128
// edges/block (2 tiles share staged We). k_xw: MFMA GEMM. k_aggr: head-split
// (blockIdx.y = head) online-softmax aggregation -> scalar state, 2-3x TLP.
// Machine model (R8-R10): waves/SIMD = 256/VGPR; never force 4 waves/EU on
// fat kernels. k_fused bank conflicts are latency-hidden (R16 proof).
// ---------------------------------------------------------------------------

typedef __attribute__((ext_vector_type(8))) short short8v;
typedef __attribute__((ext_vector_type(4))) float f32x4;

__device__ __forceinline__ unsigned short f2bf(float f) {
    union { float f; unsigned u; } v; v.f = f;
    unsigned r = v.u + 0x7fff + ((v.u >> 16) & 1);
    return (unsigned short)(r >> 16);
}
__device__ __forceinline__ float bf2f(unsigned short b) {
    union { unsigned u; float f; } v; v.u = ((unsigned)b) << 16;
    return v.f;
}

__device__ __forceinline__ int xcd_swizzle(int bid, int nwg) {
    int sq = nwg >> 3, sr = nwg & 7;
    int xcd = bid & 7, idx = bid >> 3;
    return (xcd < sr ? xcd * (sq + 1) : sr * (sq + 1) + (xcd - sr) * sq) + idx;
}

__global__ void k_deg(const int* __restrict__ dst, int E, int* __restrict__ deg) {
    int e = blockIdx.x * blockDim.x + threadIdx.x;
    if (e < E) atomicAdd(&deg[dst[e]], 1);
}

// ---- multi-block exclusive scan: deg[N] -> row_ptr[N+1], woff[N] ----------
__global__ void k_scan1(const int* __restrict__ deg, int N,
                        int* __restrict__ incl, int* __restrict__ bsum) {
    __shared__ int ws4[4];
    const int tid = threadIdx.x;
    const int lane = tid & 63, w = tid >> 6;
    const int base = blockIdx.x * 2048;
    int v[8];
    int s = 0;
#pragma unroll
    for (int j = 0; j < 8; ++j) {
        int i = base + tid * 8 + j;
        v[j] = (i < N) ? deg[i] : 0;
        s += v[j];
    }
    int ps = s;
#pragma unroll
    for (int off = 1; off < 64; off <<= 1) {
        int t = __shfl_up(ps, off);
        if (lane >= off) ps += t;
    }
    if (lane == 63) ws4[w] = ps;
    __syncthreads();
    int woffs = 0;
#pragma unroll
    for (int k = 0; k < 4; ++k)
        if (k < w) woffs += ws4[k];
    int run = ps - s + woffs;
#pragma unroll
    for (int j = 0; j < 8; ++j) {
        run += v[j];
        int i = base + tid * 8 + j;
        if (i < N) incl[i] = run;
    }
    if (tid == 255) bsum[blockIdx.x] = run;
}

__global__ void k_scan2(int* __restrict__ bsum, int nb) {
    if (threadIdx.x == 0) {
        int c = 0;
        for (int k = 0; k < nb; ++k) { int t = bsum[k]; bsum[k] = c; c += t; }
    }
}

__global__ void k_scan3(const int* __restrict__ incl, const int* __restrict__ deg,
                        const int* __restrict__ boff, int N,
                        int* __restrict__ row_ptr, int* __restrict__ woff) {
    int i = blockIdx.x * blockDim.x + threadIdx.x;
    if (i < N) {
        int v = incl[i] + boff[i >> 11];
        row_ptr[i + 1] = v;
        woff[i] = v - deg[i];
        if (i == 0) row_ptr[0] = 0;
    }
}

// scatter edges into CSR order; also materialize src/dst in CSR order
__global__ void k_scatter(const int* __restrict__ src, const int* __restrict__ dst,
                          int E, int* __restrict__ woff, int* __restrict__ cidx,
                          int* __restrict__ s_csr, int* __restrict__ d_csr) {
    int e = blockIdx.x * blockDim.x + threadIdx.x;
    if (e < E) {
        int d = dst[e];
        int p = atomicAdd(&woff[d], 1);
        cidx[p] = e;
        s_csr[p] = src[e];
        d_csr[p] = d;
    }
}

// segmented sum of edge attrs per dst (CSR order): 32-lane group per node
__global__ void k_easeg(const float* __restrict__ ea, const int* __restrict__ cidx,
                        const int* __restrict__ row_ptr, int N,
                        float* __restrict__ easum) {
    const int t = blockIdx.x * blockDim.x + threadIdx.x;
    const int w = t >> 5;
    const int lane = threadIdx.x & 31;
    if (w >= N) return;
    const int beg = row_ptr[w], end = row_ptr[w + 1];
    float s = 0.f;
    for (int i = beg; i < end; ++i) {
        int e = cidx[i];
        s += ea[(size_t)e * 32 + lane];
    }
    easum[(size_t)w * 32 + lane] = s;
}

// ---- MFMA GEMM: {xl,xr}[n][col] = in[n][:128] . W{l,r}[:, col] + b ---------
template <int HC, bool INBF>
__global__ __launch_bounds__(256, 2) void k_xw(
        const void* __restrict__ in_, int N,
        const float* __restrict__ Wl, const float* __restrict__ bl,
        const float* __restrict__ Wr, const float* __restrict__ br,
        unsigned short* __restrict__ outl, unsigned short* __restrict__ outr) {
    __shared__ __align__(16) unsigned short Wsb[64][136];  // [c][k], +8 pad
    const int tid = threadIdx.x;
    const int m0 = blockIdx.x * 64;
    const int cc0 = blockIdx.y * 64;

    const int lane = tid & 63;
    const int w = tid >> 6;
    const int lm = lane & 15;
    const int lk = lane >> 4;

    int node_in = m0 + w * 16 + lm;
    if (node_in >= N) node_in = N - 1;
    short8v afrag[4];
#pragma unroll
    for (int kc = 0; kc < 4; ++kc) {
        if constexpr (INBF) {
            const unsigned short* in = (const unsigned short*)in_;
            afrag[kc] = *(const short8v*)&in[(size_t)node_in * 128 + kc * 32 + lk * 8];
        } else {
            const float* in = (const float*)in_;
            const float4* ap = (const float4*)(in + (size_t)node_in * 128 + kc * 32 + lk * 8);
            float4 v0 = ap[0], v1 = ap[1];
            afrag[kc][0] = (short)f2bf(v0.x); afrag[kc][1] = (short)f2bf(v0.y);
            afrag[kc][2] = (short)f2bf(v0.z); afrag[kc][3] = (short)f2bf(v0.w);
            afrag[kc][4] = (short)f2bf(v1.x); afrag[kc][5] = (short)f2bf(v1.y);
            afrag[kc][6] = (short)f2bf(v1.z); afrag[kc][7] = (short)f2bf(v1.w);
        }
    }

#pragma unroll
    for (int mat = 0; mat < 2; ++mat) {
        const float* W = mat ? Wr : Wl;
        const float* b = mat ? br : bl;
        unsigned short* out = mat ? outr : outl;
        __syncthreads();
        for (int i4 = tid; i4 < 128 * 16; i4 += 256) {
            int k = i4 >> 4, c4 = i4 & 15;
            float4 v = *(const float4*)&W[(size_t)k * HC + cc0 + c4 * 4];
            Wsb[c4 * 4 + 0][k] = f2bf(v.x);
            Wsb[c4 * 4 + 1][k] = f2bf(v.y);
            Wsb[c4 * 4 + 2][k] = f2bf(v.z);
            Wsb[c4 * 4 + 3][k] = f2bf(v.w);
        }
        __syncthreads();

#pragma unroll
        for (int cg = 0; cg < 4; ++cg) {
            f32x4 acc = {0.f, 0.f, 0.f, 0.f};
#pragma unroll
            for (int kc = 0; kc < 4; ++kc) {
                short8v bfrag = *(const short8v*)&Wsb[cg * 16 + lm][kc * 32 + lk * 8];
                acc = __builtin_amdgcn_mfma_f32_16x16x32_bf16(afrag[kc], bfrag, acc, 0, 0, 0);
            }
            const int col = cc0 + cg * 16 + lm;
            const float bb = b[col];
#pragma unroll
            for (int r = 0; r < 4; ++r) {
                int n = m0 + w * 16 + lk * 4 + r;
                if (n < N) out[(size_t)n * HC + col] = f2bf(acc[r] + bb);
            }
        }
    }
}

// ---- EE GEMM (self-loop path): out[m][col] = A[m][:32] . We[:, col] (bf16) -
template <int HC>
__global__ __launch_bounds__(256, 2) void k_ee(
        const float* __restrict__ A, int M,
        const float* __restrict__ We,
        unsigned short* __restrict__ out) {
    __shared__ float As[32][68];
    __shared__ float Ws[32][64];
    const int tid = threadIdx.x;
    const int m0 = blockIdx.x * 64;
    const int cc = blockIdx.y;

#pragma unroll
    for (int t = 0; t < 2; ++t) {
        int idx4 = tid + t * 256;
        int r = idx4 >> 3, q = idx4 & 7;
        int n = m0 + r;
        float4 v = make_float4(0.f, 0.f, 0.f, 0.f);
        if (n < M) v = ((const float4*)A)[(size_t)n * 8 + q];
        As[q * 4 + 0][r] = v.x;
        As[q * 4 + 1][r] = v.y;
        As[q * 4 + 2][r] = v.z;
        As[q * 4 + 3][r] = v.w;
    }
#pragma unroll
    for (int i = tid; i < 32 * 64; i += 256) {
        int k = i >> 6, c = i & 63;
        Ws[k][c] = We[(size_t)k * HC + cc * 64 + c];
    }
    __syncthreads();

    const int rm = tid >> 4, rn = tid & 15;
    float acc[4][4];
#pragma unroll
    for (int i = 0; i < 4; ++i)
#pragma unroll
        for (int j = 0; j < 4; ++j) acc[i][j] = 0.f;
#pragma unroll
    for (int k = 0; k < 32; ++k) {
        float4 a = *(const float4*)&As[k][rm * 4];
        float4 bv = *(const float4*)&Ws[k][rn * 4];
        acc[0][0] += a.x * bv.x; acc[0][1] += a.x * bv.y;
        acc[0][2] += a.x * bv.z; acc[0][3] += a.x * bv.w;
        acc[1][0] += a.y * bv.x; acc[1][1] += a.y * bv.y;
        acc[1][2] += a.y * bv.z; acc[1][3] += a.y * bv.w;
        acc[2][0] += a.z * bv.x; acc[2][1] += a.z * bv.y;
        acc[2][2] += a.z * bv.z; acc[2][3] += a.z * bv.w;
        acc[3][0] += a.w * bv.x; acc[3][1] += a.w * bv.y;
        acc[3][2] += a.w * bv.z; acc[3][3] += a.w * bv.w;
    }
#pragma unroll
    for (int i = 0; i < 4; ++i) {
        int n = m0 + rm * 4 + i;
        if (n < M) {
            ushort4 o;
            o.x = f2bf(acc[i][0]);
            o.y = f2bf(acc[i][1]);
            o.z = f2bf(acc[i][2]);
            o.w = f2bf(acc[i][3]);
            *(ushort4*)&out[(size_t)n * HC + cc * 64 + rn * 4] = o;
        }
    }
}

// ---- fused edge logits in CSR order, MFMA (R13-validated core) -------------
// 128 edges/block (2 tiles of 64 share the staged We).
template <int H>
__global__ __launch_bounds__(256, 2) void k_fused(
        const unsigned short* __restrict__ xlb, const unsigned short* __restrict__ xrb,
        const float* __restrict__ ea,
        const int* __restrict__ cidx, const int* __restrict__ s_csr,
        const int* __restrict__ d_csr, int E,
        const float* __restrict__ We, const float* __restrict__ att,
        float* __restrict__ alpha) {
    constexpr int HC = H * 64;
    __shared__ __align__(16) unsigned short Wsb[HC][40];  // [col][k], 80B rows
    __shared__ int Es[128], Ss[128], Ds[128];
    const int tid = threadIdx.x;
    const int wg = xcd_swizzle(blockIdx.x, gridDim.x);
    const int i0 = wg * 128;

    if (tid < 128) {
        int i = i0 + tid;
        bool ok = i < E;
        Es[tid] = ok ? cidx[i] : 0;
        Ss[tid] = ok ? s_csr[i] : 0;
        Ds[tid] = ok ? d_csr[i] : 0;
    }
    for (int idx4 = tid; idx4 < 32 * (HC / 4); idx4 += 256) {
        int k = idx4 / (HC / 4), c4 = idx4 % (HC / 4);
        float4 v = ((const float4*)We)[idx4];
        Wsb[c4 * 4 + 0][k] = f2bf(v.x);
        Wsb[c4 * 4 + 1][k] = f2bf(v.y);
        Wsb[c4 * 4 + 2][k] = f2bf(v.z);
        Wsb[c4 * 4 + 3][k] = f2bf(v.w);
    }
    __syncthreads();

    const int lane = tid & 63;
    const int w = tid >> 6;
    const int lm = lane & 15;
    const int lk = lane >> 4;
    const int k0 = lk * 8;

#pragma unroll
    for (int t = 0; t < 2; ++t) {
        const int tb = t * 64;
        short8v afrag;
        {
            int eidx = Es[tb + w * 16 + lm];
            const float4* ap = (const float4*)(ea + (size_t)eidx * 32 + k0);
            float4 v0 = ap[0], v1 = ap[1];
            afrag[0] = (short)f2bf(v0.x); afrag[1] = (short)f2bf(v0.y);
            afrag[2] = (short)f2bf(v0.z); afrag[3] = (short)f2bf(v0.w);
            afrag[4] = (short)f2bf(v1.x); afrag[5] = (short)f2bf(v1.y);
            afrag[6] = (short)f2bf(v1.z); afrag[7] = (short)f2bf(v1.w);
        }
        int sN[4], dN[4], gOk[4];
#pragma unroll
        for (int r = 0; r < 4; ++r) {
            int el = tb + w * 16 + lk * 4 + r;
            sN[r] = Ss[el];
            dN[r] = Ds[el];
            gOk[r] = (i0 + el) < E;
        }

#pragma unroll
        for (int cc = 0; cc < H; ++cc) {
            float part[4] = {0.f, 0.f, 0.f, 0.f};
#pragma unroll
            for (int cg = 0; cg < 4; ++cg) {
                const int col = cc * 64 + cg * 16 + lm;
                short8v bfrag = *(const short8v*)&Wsb[col][k0];
                f32x4 dacc = {0.f, 0.f, 0.f, 0.f};
                dacc = __builtin_amdgcn_mfma_f32_16x16x32_bf16(afrag, bfrag, dacc, 0, 0, 0);
                float attv = att[col];
#pragma unroll
                for (int r = 0; r < 4; ++r) {
                    float xa = bf2f(xlb[(size_t)sN[r] * HC + col]);
                    float xb = bf2f(xrb[(size_t)dN[r] * HC + col]);
                    float mv = xa + xb + dacc[r];
                    mv = mv > 0.f ? mv : 0.2f * mv;
                    part[r] += mv * attv;
                }
            }
#pragma unroll
            for (int off = 1; off < 16; off <<= 1)
#pragma unroll
                for (int r = 0; r < 4; ++r) part[r] += __shfl_xor(part[r], off);
            if (lm == 0) {
#pragma unroll
                for (int r = 0; r < 4; ++r) {
                    if (gOk[r]) {
                        int gi = i0 + tb + w * 16 + lk * 4 + r;
                        alpha[(size_t)gi * H + cc] = part[r];
                    }
                }
            }
        }
    }
}

// online-softmax aggregate, HEAD-SPLIT: blockIdx.y = head. One wave per
// (node, head); lane = channel within head. Scalar state, 4-edge unroll.
template <int H, bool RELU, bool OUTBF>
__global__ __launch_bounds__(256) void k_aggr(
        const unsigned short* __restrict__ xlb, const unsigned short* __restrict__ xrb,
        const unsigned short* __restrict__ EEself, const int* __restrict__ deg,
        const float* __restrict__ att,
        const int* __restrict__ s_csr, const int* __restrict__ row_ptr,
        const float* __restrict__ alpha,
        const float* __restrict__ bias, int Nn,
        void* __restrict__ out_) {
    constexpr int HC = H * 64;
    const int lane = threadIdx.x & 63;
    const int h = blockIdx.y;
    const int wg = xcd_swizzle(blockIdx.x, gridDim.x);
    const int n = wg * 4 + ((int)threadIdx.x >> 6);
    if (n >= Nn) return;
    const int co = h * 64 + lane;   // this lane's channel

    // ---- self-loop logit, seeds the online softmax ----
    float m, den, acc;
    {
        int dg = deg[n];
        float inv = 1.f / (float)(dg > 0 ? dg : 1);
        float xlv = bf2f(xlb[(size_t)n * HC + co]);
        float v = xlv + bf2f(xrb[(size_t)n * HC + co])
                + bf2f(EEself[(size_t)n * HC + co]) * inv;
        v = v > 0.f ? v : 0.2f * v;
        float al = v * att[co];
#pragma unroll
        for (int off = 1; off < 64; off <<= 1) al += __shfl_xor(al, off);
        m = al;
        den = 1.f;
        acc = xlv;
    }

    const int beg = row_ptr[n], end = row_ptr[n + 1];
    int i = beg;
    for (; i + 3 < end; i += 4) {
        int s0 = s_csr[i], s1 = s_csr[i + 1], s2 = s_csr[i + 2], s3 = s_csr[i + 3];
        float a0 = alpha[(size_t)i * H + h];
        float a1 = alpha[(size_t)(i + 1) * H + h];
        float a2 = alpha[(size_t)(i + 2) * H + h];
        float a3 = alpha[(size_t)(i + 3) * H + h];
        float xv0 = bf2f(xlb[(size_t)s0 * HC + co]);
        float xv1 = bf2f(xlb[(size_t)s1 * HC + co]);
        float xv2 = bf2f(xlb[(size_t)s2 * HC + co]);
        float xv3 = bf2f(xlb[(size_t)s3 * HC + co]);
        float mx01 = fmaxf(a0, a1);
        float mx23 = fmaxf(a2, a3);
        float nm = fmaxf(m, fmaxf(mx01, mx23));
        float corr = __expf(m - nm);
        float p0 = __expf(a0 - nm);
        float p1 = __expf(a1 - nm);
        float p2 = __expf(a2 - nm);
        float p3 = __expf(a3 - nm);
        den = den * corr + (p0 + p1) + (p2 + p3);
        acc = acc * corr + (p0 * xv0 + p1 * xv1) + (p2 * xv2 + p3 * xv3);
        m = nm;
    }
    for (; i < end; ++i) {
        int s = s_csr[i];
        float a = alpha[(size_t)i * H + h];
        float xv = bf2f(xlb[(size_t)s * HC + co]);
        float nm = fmaxf(m, a);
        float corr = __expf(m - nm);
        float p = __expf(a - nm);
        den = den * corr + p;
        acc = acc * corr + p * xv;
        m = nm;
    }
    float r = acc / den + bias[co];
    if (RELU) r = r > 0.f ? r : 0.01f * r;
    if constexpr (OUTBF)
        ((unsigned short*)out_)[(size_t)n * HC + co] = f2bf(r);
    else
        ((float*)out_)[(size_t)n * HC + co] = r;
}

// global_add_pool over sorted batch
__global__ void k_pool(const float* __restrict__ h2, const int* __restrict__ batch,
                       int Nn, float* __restrict__ g) {
    const int c = threadIdx.x;  // 0..191
    const int n0 = blockIdx.x * 128;
    if (n0 >= Nn) return;
    const int n1 = (n0 + 128 < Nn) ? n0 + 128 : Nn;
    float s = 0.f;
    int cur = batch[n0];
    for (int n = n0; n < n1; ++n) {
        int b = batch[n];
        if (b != cur) {
            atomicAdd(&g[cur * 192 + c], s);
            s = 0.f;
            cur = b;
        }
        s += h2[(size_t)n * 192 + c];
    }
    atomicAdd(&g[cur * 192 + c], s);
}

__global__ void k_mlp(const float* __restrict__ g,
                      const float* W1, const float* c1, const float* W2, const float* c2,
                      const float* W3, const float* c3, const float* W4, const float* c4,
                      const float* W5, const float* c5, const float* W6, const float* c6,
                      float* __restrict__ out) {
    __shared__ float t0[8 * 192];
    __shared__ float t1[8 * 64];
    __shared__ float t2[8 * 32];
    __shared__ float t3[8 * 16];
    __shared__ float t4[8 * 8];
    const int tid = threadIdx.x;
    for (int i = tid; i < 8 * 192; i += 256) t0[i] = g[i];
    __syncthreads();
    for (int i = tid; i < 8 * 64; i += 256) {
        int r = i >> 6, c = i & 63;
        float s = c1[c];
        for (int k = 0; k < 192; ++k) s += t0[r * 192 + k] * W1[k * 64 + c];
        t1[i] = s > 0.f ? s : 0.01f * s;
    }
    __syncthreads();
    for (int i = tid; i < 8 * 32; i += 256) {
        int r = i >> 5, c = i & 31;
        float s = c2[c];
        for (int k = 0; k < 64; ++k) s += t1[r * 64 + k] * W2[k * 32 + c];
        t2[i] = s > 0.f ? s : 0.01f * s;
    }
    __syncthreads();
    for (int i = tid; i < 8 * 16; i += 256) {
        int r = i >> 4, c = i & 15;
        float s = c3[c];
        for (int k = 0; k < 32; ++k) s += t2[r * 32 + k] * W3[k * 16 + c];
        t3[i] = s > 0.f ? s : 0.01f * s;
    }
    __syncthreads();
    for (int i = tid; i < 8 * 8; i += 256) {
        int r = i >> 3, c = i & 7;
        float s = c4[c];
        for (int k = 0; k < 16; ++k) s += t3[r * 16 + k] * W4[k * 8 + c];
        t4[i] = s > 0.f ? s : 0.01f * s;
    }
    __syncthreads();
    if (tid < 8) {
        float s = c5[0];
        for (int k = 0; k < 8; ++k) s += t4[tid * 8 + k] * W5[k];
        s = s * W6[0] + c6[0];
        out[tid] = s;
    }
}

extern "C" void kernel_launch(void* const* d_in, const int* in_sizes, int n_in,
                              void* d_out, int out_size, void* d_ws, size_t ws_size,
                              hipStream_t stream) {
    const float* x     = (const float*)d_in[0];
    const int*   eidx  = (const int*)d_in[1];
    const float* ea    = (const float*)d_in[2];
    const int*   batch = (const int*)d_in[3];
    const float* Wl1 = (const float*)d_in[4];
    const float* bl1 = (const float*)d_in[5];
    const float* Wr1 = (const float*)d_in[6];
    const float* br1 = (const float*)d_in[7];
    const float* We1 = (const float*)d_in[8];
    const float* att1 = (const float*)d_in[9];
    const float* bias1 = (const float*)d_in[10];
    const float* Wl2 = (const float*)d_in[11];
    const float* bl2 = (const float*)d_in[12];
    const float* Wr2 = (const float*)d_in[13];
    const float* br2 = (const float*)d_in[14];
    const float* We2 = (const float*)d_in[15];
    const float* att2 = (const float*)d_in[16];
    const float* bias2 = (const float*)d_in[17];
    const float* W1 = (const float*)d_in[18];
    const float* c1 = (const float*)d_in[19];
    const float* W2 = (const float*)d_in[20];
    const float* c2 = (const float*)d_in[21];
    const float* W3 = (const float*)d_in[22];
    const float* c3 = (const float*)d_in[23];
    const float* W4 = (const float*)d_in[24];
    const float* c4 = (const float*)d_in[25];
    const float* W5 = (const float*)d_in[26];
    const float* c5 = (const float*)d_in[27];
    const float* W6 = (const float*)d_in[28];
    const float* c6 = (const float*)d_in[29];

    const int N = in_sizes[0] / 128;
    const int E = in_sizes[1] / 2;
    const int* srcs = eidx;
    const int* dsts = eidx + E;

    char* p = (char*)d_ws;
    auto alloc = [&](size_t bytes) -> char* {
        char* r = p;
        p += (bytes + 255) & ~(size_t)255;
        return r;
    };
    int*            deg     = (int*)alloc((size_t)N * 4);
    int*            row_ptr = (int*)alloc((size_t)(N + 1) * 4);
    int*            woff    = (int*)alloc((size_t)N * 4);
    int*            cidx    = (int*)alloc((size_t)E * 4);
    int*            s_csr   = (int*)alloc((size_t)E * 4);
    int*            d_csr   = (int*)alloc((size_t)E * 4);
    int*            incl    = (int*)alloc((size_t)N * 4);
    int*            bsum    = (int*)alloc(64 * 4);
    float*          easum   = (float*)alloc((size_t)N * 32 * 4);
    unsigned short* EEself  = (unsigned short*)alloc((size_t)N * 192 * 2);
    unsigned short* xlb     = (unsigned short*)alloc((size_t)N * 192 * 2);
    unsigned short* xrb     = (unsigned short*)alloc((size_t)N * 192 * 2);
    unsigned short* h1b     = (unsigned short*)alloc((size_t)N * 128 * 2);
    float*          h2      = (float*)alloc((size_t)N * 192 * 4);
    float*          alpha   = (float*)alloc((size_t)E * 3 * 4);
    float*          gp      = (float*)alloc(8 * 192 * 4);

    hipMemsetAsync(deg, 0, (size_t)N * 4, stream);
    hipMemsetAsync(gp, 0, 8 * 192 * 4, stream);

    // CSR build
    const int nb = (N + 2047) / 2048;
    k_deg<<<(E + 255) / 256, 256, 0, stream>>>(dsts, E, deg);
    k_scan1<<<nb, 256, 0, stream>>>(deg, N, incl, bsum);
    k_scan2<<<1, 64, 0, stream>>>(bsum, nb);
    k_scan3<<<(N + 255) / 256, 256, 0, stream>>>(incl, deg, bsum, N, row_ptr, woff);
    k_scatter<<<(E + 255) / 256, 256, 0, stream>>>(srcs, dsts, E, woff, cidx, s_csr, d_csr);

    const int mt = (N + 63) / 64;     // GEMM row tiles
    const int et = (E + 127) / 128;   // fused edge tiles (128 edges/block)
    const int nblk = (N + 3) / 4;     // node-parallel blocks (1 wave/node)

    k_easeg<<<(N * 32 + 255) / 256, 256, 0, stream>>>(ea, cidx, row_ptr, N, easum);

    // ---------------- conv1: H=2, HC=128 ----------------
    k_xw<128, false><<<dim3(mt, 2), 256, 0, stream>>>(x, N, Wl1, bl1, Wr1, br1, xlb, xrb);
    k_ee<128><<<dim3(mt, 2), 256, 0, stream>>>(easum, N, We1, EEself);
    k_fused<2><<<et, 256, 0, stream>>>(xlb, xrb, ea, cidx, s_csr, d_csr, E, We1, att1, alpha);
    k_aggr<2, true, true><<<dim3(nblk, 2), 256, 0, stream>>>(
        xlb, xrb, EEself, deg, att1, s_csr, row_ptr, alpha, bias1, N, h1b);

    // ---------------- conv2: H=3, HC=192 ----------------
    k_xw<192, true><<<dim3(mt, 3), 256, 0, stream>>>(h1b, N, Wl2, bl2, Wr2, br2, xlb, xrb);
    k_ee<192><<<dim3(mt, 3), 256, 0, stream>>>(easum, N, We2, EEself);
    k_fused<3><<<et, 256, 0, stream>>>(xlb, xrb, ea, cidx, s_csr, d_csr, E, We2, att2, alpha);
    k_aggr<3, true, false><<<dim3(nblk, 3), 256, 0, stream>>>(
        xlb, xrb, EEself, deg, att2, s_csr, row_ptr, alpha, bias2, N, h2);

    k_pool<<<(N + 127) / 128, 192, 0, stream>>>(h2, batch, N, gp);
    k_mlp<<<1, 256, 0, stream>>>(gp, W1, c1, W2, c2, W3, c3, W4, c4, W5, c5, W6, c6,
                                 (float*)d_out);
}

// Round 21
// 704.027 us; speedup vs baseline: 1.0853x; 1.0853x over previous
//
#include <hip/hip_runtime.h>
#include <hip/hip_bf16.h>
#include <math.h>

// ---------------------------------------------------------------------------
// GATv2 x2 + global_add_pool + MLP head.  (R19-validated configuration, 697us)
// xl/xr/h1/EEself as bf16. k_fused: R13-validated MFMA edge kernel, 128
// edges/block (2 tiles share staged We). k_xw: MFMA GEMM. Self-logit folded
// into online-softmax aggregation (k_aggr, all-heads, (256,3)).
// Machine model (R8-R10): waves/SIMD = 256/VGPR; never force 4 waves/EU on
// fat kernels. k_fused bank conflicts are latency-hidden (R16 proof).
// R20 lesson: head-splitting k_aggr multiplies index/alpha traffic without
// shortening the serial softmax chain -> regression. Keep all-heads form.
// ---------------------------------------------------------------------------

typedef __attribute__((ext_vector_type(8))) short short8v;
typedef __attribute__((ext_vector_type(4))) float f32x4;

__device__ __forceinline__ unsigned short f2bf(float f) {
    union { float f; unsigned u; } v; v.f = f;
    unsigned r = v.u + 0x7fff + ((v.u >> 16) & 1);
    return (unsigned short)(r >> 16);
}
__device__ __forceinline__ float bf2f(unsigned short b) {
    union { unsigned u; float f; } v; v.u = ((unsigned)b) << 16;
    return v.f;
}

__device__ __forceinline__ int xcd_swizzle(int bid, int nwg) {
    int sq = nwg >> 3, sr = nwg & 7;
    int xcd = bid & 7, idx = bid >> 3;
    return (xcd < sr ? xcd * (sq + 1) : sr * (sq + 1) + (xcd - sr) * sq) + idx;
}

__global__ void k_deg(const int* __restrict__ dst, int E, int* __restrict__ deg) {
    int e = blockIdx.x * blockDim.x + threadIdx.x;
    if (e < E) atomicAdd(&deg[dst[e]], 1);
}

// ---- multi-block exclusive scan: deg[N] -> row_ptr[N+1], woff[N] ----------
__global__ void k_scan1(const int* __restrict__ deg, int N,
                        int* __restrict__ incl, int* __restrict__ bsum) {
    __shared__ int ws4[4];
    const int tid = threadIdx.x;
    const int lane = tid & 63, w = tid >> 6;
    const int base = blockIdx.x * 2048;
    int v[8];
    int s = 0;
#pragma unroll
    for (int j = 0; j < 8; ++j) {
        int i = base + tid * 8 + j;
        v[j] = (i < N) ? deg[i] : 0;
        s += v[j];
    }
    int ps = s;
#pragma unroll
    for (int off = 1; off < 64; off <<= 1) {
        int t = __shfl_up(ps, off);
        if (lane >= off) ps += t;
    }
    if (lane == 63) ws4[w] = ps;
    __syncthreads();
    int woffs = 0;
#pragma unroll
    for (int k = 0; k < 4; ++k)
        if (k < w) woffs += ws4[k];
    int run = ps - s + woffs;
#pragma unroll
    for (int j = 0; j < 8; ++j) {
        run += v[j];
        int i = base + tid * 8 + j;
        if (i < N) incl[i] = run;
    }
    if (tid == 255) bsum[blockIdx.x] = run;
}

__global__ void k_scan2(int* __restrict__ bsum, int nb) {
    if (threadIdx.x == 0) {
        int c = 0;
        for (int k = 0; k < nb; ++k) { int t = bsum[k]; bsum[k] = c; c += t; }
    }
}

__global__ void k_scan3(const int* __restrict__ incl, const int* __restrict__ deg,
                        const int* __restrict__ boff, int N,
                        int* __restrict__ row_ptr, int* __restrict__ woff) {
    int i = blockIdx.x * blockDim.x + threadIdx.x;
    if (i < N) {
        int v = incl[i] + boff[i >> 11];
        row_ptr[i + 1] = v;
        woff[i] = v - deg[i];
        if (i == 0) row_ptr[0] = 0;
    }
}

// scatter edges into CSR order; also materialize src/dst in CSR order
__global__ void k_scatter(const int* __restrict__ src, const int* __restrict__ dst,
                          int E, int* __restrict__ woff, int* __restrict__ cidx,
                          int* __restrict__ s_csr, int* __restrict__ d_csr) {
    int e = blockIdx.x * blockDim.x + threadIdx.x;
    if (e < E) {
        int d = dst[e];
        int p = atomicAdd(&woff[d], 1);
        cidx[p] = e;
        s_csr[p] = src[e];
        d_csr[p] = d;
    }
}

// segmented sum of edge attrs per dst (CSR order): 32-lane group per node
__global__ void k_easeg(const float* __restrict__ ea, const int* __restrict__ cidx,
                        const int* __restrict__ row_ptr, int N,
                        float* __restrict__ easum) {
    const int t = blockIdx.x * blockDim.x + threadIdx.x;
    const int w = t >> 5;
    const int lane = threadIdx.x & 31;
    if (w >= N) return;
    const int beg = row_ptr[w], end = row_ptr[w + 1];
    float s = 0.f;
    for (int i = beg; i < end; ++i) {
        int e = cidx[i];
        s += ea[(size_t)e * 32 + lane];
    }
    easum[(size_t)w * 32 + lane] = s;
}

// ---- MFMA GEMM: {xl,xr}[n][col] = in[n][:128] . W{l,r}[:, col] + b ---------
template <int HC, bool INBF>
__global__ __launch_bounds__(256, 2) void k_xw(
        const void* __restrict__ in_, int N,
        const float* __restrict__ Wl, const float* __restrict__ bl,
        const float* __restrict__ Wr, const float* __restrict__ br,
        unsigned short* __restrict__ outl, unsigned short* __restrict__ outr) {
    __shared__ __align__(16) unsigned short Wsb[64][136];  // [c][k], +8 pad
    const int tid = threadIdx.x;
    const int m0 = blockIdx.x * 64;
    const int cc0 = blockIdx.y * 64;

    const int lane = tid & 63;
    const int w = tid >> 6;
    const int lm = lane & 15;
    const int lk = lane >> 4;

    int node_in = m0 + w * 16 + lm;
    if (node_in >= N) node_in = N - 1;
    short8v afrag[4];
#pragma unroll
    for (int kc = 0; kc < 4; ++kc) {
        if constexpr (INBF) {
            const unsigned short* in = (const unsigned short*)in_;
            afrag[kc] = *(const short8v*)&in[(size_t)node_in * 128 + kc * 32 + lk * 8];
        } else {
            const float* in = (const float*)in_;
            const float4* ap = (const float4*)(in + (size_t)node_in * 128 + kc * 32 + lk * 8);
            float4 v0 = ap[0], v1 = ap[1];
            afrag[kc][0] = (short)f2bf(v0.x); afrag[kc][1] = (short)f2bf(v0.y);
            afrag[kc][2] = (short)f2bf(v0.z); afrag[kc][3] = (short)f2bf(v0.w);
            afrag[kc][4] = (short)f2bf(v1.x); afrag[kc][5] = (short)f2bf(v1.y);
            afrag[kc][6] = (short)f2bf(v1.z); afrag[kc][7] = (short)f2bf(v1.w);
        }
    }

#pragma unroll
    for (int mat = 0; mat < 2; ++mat) {
        const float* W = mat ? Wr : Wl;
        const float* b = mat ? br : bl;
        unsigned short* out = mat ? outr : outl;
        __syncthreads();
        for (int i4 = tid; i4 < 128 * 16; i4 += 256) {
            int k = i4 >> 4, c4 = i4 & 15;
            float4 v = *(const float4*)&W[(size_t)k * HC + cc0 + c4 * 4];
            Wsb[c4 * 4 + 0][k] = f2bf(v.x);
            Wsb[c4 * 4 + 1][k] = f2bf(v.y);
            Wsb[c4 * 4 + 2][k] = f2bf(v.z);
            Wsb[c4 * 4 + 3][k] = f2bf(v.w);
        }
        __syncthreads();

#pragma unroll
        for (int cg = 0; cg < 4; ++cg) {
            f32x4 acc = {0.f, 0.f, 0.f, 0.f};
#pragma unroll
            for (int kc = 0; kc < 4; ++kc) {
                short8v bfrag = *(const short8v*)&Wsb[cg * 16 + lm][kc * 32 + lk * 8];
                acc = __builtin_amdgcn_mfma_f32_16x16x32_bf16(afrag[kc], bfrag, acc, 0, 0, 0);
            }
            const int col = cc0 + cg * 16 + lm;
            const float bb = b[col];
#pragma unroll
            for (int r = 0; r < 4; ++r) {
                int n = m0 + w * 16 + lk * 4 + r;
                if (n < N) out[(size_t)n * HC + col] = f2bf(acc[r] + bb);
            }
        }
    }
}

// ---- EE GEMM (self-loop path): out[m][col] = A[m][:32] . We[:, col] (bf16) -
template <int HC>
__global__ __launch_bounds__(256, 2) void k_ee(
        const float* __restrict__ A, int M,
        const float* __restrict__ We,
        unsigned short* __restrict__ out) {
    __shared__ float As[32][68];
    __shared__ float Ws[32][64];
    const int tid = threadIdx.x;
    const int m0 = blockIdx.x * 64;
    const int cc = blockIdx.y;

#pragma unroll
    for (int t = 0; t < 2; ++t) {
        int idx4 = tid + t * 256;
        int r = idx4 >> 3, q = idx4 & 7;
        int n = m0 + r;
        float4 v = make_float4(0.f, 0.f, 0.f, 0.f);
        if (n < M) v = ((const float4*)A)[(size_t)n * 8 + q];
        As[q * 4 + 0][r] = v.x;
        As[q * 4 + 1][r] = v.y;
        As[q * 4 + 2][r] = v.z;
        As[q * 4 + 3][r] = v.w;
    }
#pragma unroll
    for (int i = tid; i < 32 * 64; i += 256) {
        int k = i >> 6, c = i & 63;
        Ws[k][c] = We[(size_t)k * HC + cc * 64 + c];
    }
    __syncthreads();

    const int rm = tid >> 4, rn = tid & 15;
    float acc[4][4];
#pragma unroll
    for (int i = 0; i < 4; ++i)
#pragma unroll
        for (int j = 0; j < 4; ++j) acc[i][j] = 0.f;
#pragma unroll
    for (int k = 0; k < 32; ++k) {
        float4 a = *(const float4*)&As[k][rm * 4];
        float4 bv = *(const float4*)&Ws[k][rn * 4];
        acc[0][0] += a.x * bv.x; acc[0][1] += a.x * bv.y;
        acc[0][2] += a.x * bv.z; acc[0][3] += a.x * bv.w;
        acc[1][0] += a.y * bv.x; acc[1][1] += a.y * bv.y;
        acc[1][2] += a.y * bv.z; acc[1][3] += a.y * bv.w;
        acc[2][0] += a.z * bv.x; acc[2][1] += a.z * bv.y;
        acc[2][2] += a.z * bv.z; acc[2][3] += a.z * bv.w;
        acc[3][0] += a.w * bv.x; acc[3][1] += a.w * bv.y;
        acc[3][2] += a.w * bv.z; acc[3][3] += a.w * bv.w;
    }
#pragma unroll
    for (int i = 0; i < 4; ++i) {
        int n = m0 + rm * 4 + i;
        if (n < M) {
            ushort4 o;
            o.x = f2bf(acc[i][0]);
            o.y = f2bf(acc[i][1]);
            o.z = f2bf(acc[i][2]);
            o.w = f2bf(acc[i][3]);
            *(ushort4*)&out[(size_t)n * HC + cc * 64 + rn * 4] = o;
        }
    }
}

// ---- fused edge logits in CSR order, MFMA (R13-validated core) -------------
// 128 edges/block (2 tiles of 64 share the staged We).
template <int H>
__global__ __launch_bounds__(256, 2) void k_fused(
        const unsigned short* __restrict__ xlb, const unsigned short* __restrict__ xrb,
        const float* __restrict__ ea,
        const int* __restrict__ cidx, const int* __restrict__ s_csr,
        const int* __restrict__ d_csr, int E,
        const float* __restrict__ We, const float* __restrict__ att,
        float* __restrict__ alpha) {
    constexpr int HC = H * 64;
    __shared__ __align__(16) unsigned short Wsb[HC][40];  // [col][k], 80B rows
    __shared__ int Es[128], Ss[128], Ds[128];
    const int tid = threadIdx.x;
    const int wg = xcd_swizzle(blockIdx.x, gridDim.x);
    const int i0 = wg * 128;

    if (tid < 128) {
        int i = i0 + tid;
        bool ok = i < E;
        Es[tid] = ok ? cidx[i] : 0;
        Ss[tid] = ok ? s_csr[i] : 0;
        Ds[tid] = ok ? d_csr[i] : 0;
    }
    for (int idx4 = tid; idx4 < 32 * (HC / 4); idx4 += 256) {
        int k = idx4 / (HC / 4), c4 = idx4 % (HC / 4);
        float4 v = ((const float4*)We)[idx4];
        Wsb[c4 * 4 + 0][k] = f2bf(v.x);
        Wsb[c4 * 4 + 1][k] = f2bf(v.y);
        Wsb[c4 * 4 + 2][k] = f2bf(v.z);
        Wsb[c4 * 4 + 3][k] = f2bf(v.w);
    }
    __syncthreads();

    const int lane = tid & 63;
    const int w = tid >> 6;
    const int lm = lane & 15;
    const int lk = lane >> 4;
    const int k0 = lk * 8;

#pragma unroll
    for (int t = 0; t < 2; ++t) {
        const int tb = t * 64;
        short8v afrag;
        {
            int eidx = Es[tb + w * 16 + lm];
            const float4* ap = (const float4*)(ea + (size_t)eidx * 32 + k0);
            float4 v0 = ap[0], v1 = ap[1];
            afrag[0] = (short)f2bf(v0.x); afrag[1] = (short)f2bf(v0.y);
            afrag[2] = (short)f2bf(v0.z); afrag[3] = (short)f2bf(v0.w);
            afrag[4] = (short)f2bf(v1.x); afrag[5] = (short)f2bf(v1.y);
            afrag[6] = (short)f2bf(v1.z); afrag[7] = (short)f2bf(v1.w);
        }
        int sN[4], dN[4], gOk[4];
#pragma unroll
        for (int r = 0; r < 4; ++r) {
            int el = tb + w * 16 + lk * 4 + r;
            sN[r] = Ss[el];
            dN[r] = Ds[el];
            gOk[r] = (i0 + el) < E;
        }

#pragma unroll
        for (int cc = 0; cc < H; ++cc) {
            float part[4] = {0.f, 0.f, 0.f, 0.f};
#pragma unroll
            for (int cg = 0; cg < 4; ++cg) {
                const int col = cc * 64 + cg * 16 + lm;
                short8v bfrag = *(const short8v*)&Wsb[col][k0];
                f32x4 dacc = {0.f, 0.f, 0.f, 0.f};
                dacc = __builtin_amdgcn_mfma_f32_16x16x32_bf16(afrag, bfrag, dacc, 0, 0, 0);
                float attv = att[col];
#pragma unroll
                for (int r = 0; r < 4; ++r) {
                    float xa = bf2f(xlb[(size_t)sN[r] * HC + col]);
                    float xb = bf2f(xrb[(size_t)dN[r] * HC + col]);
                    float mv = xa + xb + dacc[r];
                    mv = mv > 0.f ? mv : 0.2f * mv;
                    part[r] += mv * attv;
                }
            }
#pragma unroll
            for (int off = 1; off < 16; off <<= 1)
#pragma unroll
                for (int r = 0; r < 4; ++r) part[r] += __shfl_xor(part[r], off);
            if (lm == 0) {
#pragma unroll
                for (int r = 0; r < 4; ++r) {
                    if (gOk[r]) {
                        int gi = i0 + tb + w * 16 + lk * 4 + r;
                        alpha[(size_t)gi * H + cc] = part[r];
                    }
                }
            }
        }
    }
}

// online-softmax aggregate over CSR segment, self-logit computed inline.
// One wave per node, lane = channel, 4-edge unroll; gathers as bf16.
// OUTBF: store output as bf16 (h1 mirror for conv2's k_xw).
template <int H, bool RELU, bool OUTBF>
__global__ __launch_bounds__(256, 3) void k_aggr(
        const unsigned short* __restrict__ xlb, const unsigned short* __restrict__ xrb,
        const unsigned short* __restrict__ EEself, const int* __restrict__ deg,
        const float* __restrict__ att,
        const int* __restrict__ s_csr, const int* __restrict__ row_ptr,
        const float* __restrict__ alpha,
        const float* __restrict__ bias, int Nn,
        void* __restrict__ out_) {
    constexpr int HC = H * 64;
    const int lane = threadIdx.x & 63;
    const int wg = xcd_swizzle(blockIdx.x, gridDim.x);
    const int n = wg * 4 + ((int)threadIdx.x >> 6);
    if (n >= Nn) return;

    // ---- self-loop logit, seeds the online softmax ----
    float m[H], den[H], acc[H];
    {
        int dg = deg[n];
        float inv = 1.f / (float)(dg > 0 ? dg : 1);
        float al[H];
#pragma unroll
        for (int h = 0; h < H; ++h) {
            float xlv = bf2f(xlb[(size_t)n * HC + h * 64 + lane]);
            float v = xlv + bf2f(xrb[(size_t)n * HC + h * 64 + lane])
                    + bf2f(EEself[(size_t)n * HC + h * 64 + lane]) * inv;
            v = v > 0.f ? v : 0.2f * v;
            al[h] = v * att[h * 64 + lane];
            acc[h] = xlv;
        }
#pragma unroll
        for (int off = 1; off < 64; off <<= 1)
#pragma unroll
            for (int h = 0; h < H; ++h) al[h] += __shfl_xor(al[h], off);
#pragma unroll
        for (int h = 0; h < H; ++h) { m[h] = al[h]; den[h] = 1.f; }
    }

    const int beg = row_ptr[n], end = row_ptr[n + 1];
    int i = beg;
    for (; i + 3 < end; i += 4) {
        int s0 = s_csr[i], s1 = s_csr[i + 1], s2 = s_csr[i + 2], s3 = s_csr[i + 3];
        float a0[H], a1[H], a2[H], a3[H], xv0[H], xv1[H], xv2[H], xv3[H];
#pragma unroll
        for (int h = 0; h < H; ++h) {
            a0[h] = alpha[(size_t)i * H + h];
            a1[h] = alpha[(size_t)(i + 1) * H + h];
            a2[h] = alpha[(size_t)(i + 2) * H + h];
            a3[h] = alpha[(size_t)(i + 3) * H + h];
            xv0[h] = bf2f(xlb[(size_t)s0 * HC + h * 64 + lane]);
            xv1[h] = bf2f(xlb[(size_t)s1 * HC + h * 64 + lane]);
            xv2[h] = bf2f(xlb[(size_t)s2 * HC + h * 64 + lane]);
            xv3[h] = bf2f(xlb[(size_t)s3 * HC + h * 64 + lane]);
        }
#pragma unroll
        for (int h = 0; h < H; ++h) {
            float mx01 = fmaxf(a0[h], a1[h]);
            float mx23 = fmaxf(a2[h], a3[h]);
            float nm = fmaxf(m[h], fmaxf(mx01, mx23));
            float corr = __expf(m[h] - nm);
            float p0 = __expf(a0[h] - nm);
            float p1 = __expf(a1[h] - nm);
            float p2 = __expf(a2[h] - nm);
            float p3 = __expf(a3[h] - nm);
            den[h] = den[h] * corr + (p0 + p1) + (p2 + p3);
            acc[h] = acc[h] * corr + (p0 * xv0[h] + p1 * xv1[h])
                                   + (p2 * xv2[h] + p3 * xv3[h]);
            m[h] = nm;
        }
    }
    for (; i < end; ++i) {
        int s = s_csr[i];
#pragma unroll
        for (int h = 0; h < H; ++h) {
            float a = alpha[(size_t)i * H + h];
            float xv = bf2f(xlb[(size_t)s * HC + h * 64 + lane]);
            float nm = fmaxf(m[h], a);
            float corr = __expf(m[h] - nm);
            float p = __expf(a - nm);
            den[h] = den[h] * corr + p;
            acc[h] = acc[h] * corr + p * xv;
            m[h] = nm;
        }
    }
#pragma unroll
    for (int h = 0; h < H; ++h) {
        float r = acc[h] / den[h] + bias[h * 64 + lane];
        if (RELU) r = r > 0.f ? r : 0.01f * r;
        if constexpr (OUTBF)
            ((unsigned short*)out_)[(size_t)n * HC + h * 64 + lane] = f2bf(r);
        else
            ((float*)out_)[(size_t)n * HC + h * 64 + lane] = r;
    }
}

// global_add_pool over sorted batch
__global__ void k_pool(const float* __restrict__ h2, const int* __restrict__ batch,
                       int Nn, float* __restrict__ g) {
    const int c = threadIdx.x;  // 0..191
    const int n0 = blockIdx.x * 128;
    if (n0 >= Nn) return;
    const int n1 = (n0 + 128 < Nn) ? n0 + 128 : Nn;
    float s = 0.f;
    int cur = batch[n0];
    for (int n = n0; n < n1; ++n) {
        int b = batch[n];
        if (b != cur) {
            atomicAdd(&g[cur * 192 + c], s);
            s = 0.f;
            cur = b;
        }
        s += h2[(size_t)n * 192 + c];
    }
    atomicAdd(&g[cur * 192 + c], s);
}

__global__ void k_mlp(const float* __restrict__ g,
                      const float* W1, const float* c1, const float* W2, const float* c2,
                      const float* W3, const float* c3, const float* W4, const float* c4,
                      const float* W5, const float* c5, const float* W6, const float* c6,
                      float* __restrict__ out) {
    __shared__ float t0[8 * 192];
    __shared__ float t1[8 * 64];
    __shared__ float t2[8 * 32];
    __shared__ float t3[8 * 16];
    __shared__ float t4[8 * 8];
    const int tid = threadIdx.x;
    for (int i = tid; i < 8 * 192; i += 256) t0[i] = g[i];
    __syncthreads();
    for (int i = tid; i < 8 * 64; i += 256) {
        int r = i >> 6, c = i & 63;
        float s = c1[c];
        for (int k = 0; k < 192; ++k) s += t0[r * 192 + k] * W1[k * 64 + c];
        t1[i] = s > 0.f ? s : 0.01f * s;
    }
    __syncthreads();
    for (int i = tid; i < 8 * 32; i += 256) {
        int r = i >> 5, c = i & 31;
        float s = c2[c];
        for (int k = 0; k < 64; ++k) s += t1[r * 64 + k] * W2[k * 32 + c];
        t2[i] = s > 0.f ? s : 0.01f * s;
    }
    __syncthreads();
    for (int i = tid; i < 8 * 16; i += 256) {
        int r = i >> 4, c = i & 15;
        float s = c3[c];
        for (int k = 0; k < 32; ++k) s += t2[r * 32 + k] * W3[k * 16 + c];
        t3[i] = s > 0.f ? s : 0.01f * s;
    }
    __syncthreads();
    for (int i = tid; i < 8 * 8; i += 256) {
        int r = i >> 3, c = i & 7;
        float s = c4[c];
        for (int k = 0; k < 16; ++k) s += t3[r * 16 + k] * W4[k * 8 + c];
        t4[i] = s > 0.f ? s : 0.01f * s;
    }
    __syncthreads();
    if (tid < 8) {
        float s = c5[0];
        for (int k = 0; k < 8; ++k) s += t4[tid * 8 + k] * W5[k];
        s = s * W6[0] + c6[0];
        out[tid] = s;
    }
}

extern "C" void kernel_launch(void* const* d_in, const int* in_sizes, int n_in,
                              void* d_out, int out_size, void* d_ws, size_t ws_size,
                              hipStream_t stream) {
    const float* x     = (const float*)d_in[0];
    const int*   eidx  = (const int*)d_in[1];
    const float* ea    = (const float*)d_in[2];
    const int*   batch = (const int*)d_in[3];
    const float* Wl1 = (const float*)d_in[4];
    const float* bl1 = (const float*)d_in[5];
    const float* Wr1 = (const float*)d_in[6];
    const float* br1 = (const float*)d_in[7];
    const float* We1 = (const float*)d_in[8];
    const float* att1 = (const float*)d_in[9];
    const float* bias1 = (const float*)d_in[10];
    const float* Wl2 = (const float*)d_in[11];
    const float* bl2 = (const float*)d_in[12];
    const float* Wr2 = (const float*)d_in[13];
    const float* br2 = (const float*)d_in[14];
    const float* We2 = (const float*)d_in[15];
    const float* att2 = (const float*)d_in[16];
    const float* bias2 = (const float*)d_in[17];
    const float* W1 = (const float*)d_in[18];
    const float* c1 = (const float*)d_in[19];
    const float* W2 = (const float*)d_in[20];
    const float* c2 = (const float*)d_in[21];
    const float* W3 = (const float*)d_in[22];
    const float* c3 = (const float*)d_in[23];
    const float* W4 = (const float*)d_in[24];
    const float* c4 = (const float*)d_in[25];
    const float* W5 = (const float*)d_in[26];
    const float* c5 = (const float*)d_in[27];
    const float* W6 = (const float*)d_in[28];
    const float* c6 = (const float*)d_in[29];

    const int N = in_sizes[0] / 128;
    const int E = in_sizes[1] / 2;
    const int* srcs = eidx;
    const int* dsts = eidx + E;

    char* p = (char*)d_ws;
    auto alloc = [&](size_t bytes) -> char* {
        char* r = p;
        p += (bytes + 255) & ~(size_t)255;
        return r;
    };
    int*            deg     = (int*)alloc((size_t)N * 4);
    int*            row_ptr = (int*)alloc((size_t)(N + 1) * 4);
    int*            woff    = (int*)alloc((size_t)N * 4);
    int*            cidx    = (int*)alloc((size_t)E * 4);
    int*            s_csr   = (int*)alloc((size_t)E * 4);
    int*            d_csr   = (int*)alloc((size_t)E * 4);
    int*            incl    = (int*)alloc((size_t)N * 4);
    int*            bsum    = (int*)alloc(64 * 4);
    float*          easum   = (float*)alloc((size_t)N * 32 * 4);
    unsigned short* EEself  = (unsigned short*)alloc((size_t)N * 192 * 2);
    unsigned short* xlb     = (unsigned short*)alloc((size_t)N * 192 * 2);
    unsigned short* xrb     = (unsigned short*)alloc((size_t)N * 192 * 2);
    unsigned short* h1b     = (unsigned short*)alloc((size_t)N * 128 * 2);
    float*          h2      = (float*)alloc((size_t)N * 192 * 4);
    float*          alpha   = (float*)alloc((size_t)E * 3 * 4);
    float*          gp      = (float*)alloc(8 * 192 * 4);

    hipMemsetAsync(deg, 0, (size_t)N * 4, stream);
    hipMemsetAsync(gp, 0, 8 * 192 * 4, stream);

    // CSR build
    const int nb = (N + 2047) / 2048;
    k_deg<<<(E + 255) / 256, 256, 0, stream>>>(dsts, E, deg);
    k_scan1<<<nb, 256, 0, stream>>>(deg, N, incl, bsum);
    k_scan2<<<1, 64, 0, stream>>>(bsum, nb);
    k_scan3<<<(N + 255) / 256, 256, 0, stream>>>(incl, deg, bsum, N, row_ptr, woff);
    k_scatter<<<(E + 255) / 256, 256, 0, stream>>>(srcs, dsts, E, woff, cidx, s_csr, d_csr);

    const int mt = (N + 63) / 64;     // GEMM row tiles
    const int et = (E + 127) / 128;   // fused edge tiles (128 edges/block)
    const int nblk = (N + 3) / 4;     // node-parallel blocks (1 wave/node)

    k_easeg<<<(N * 32 + 255) / 256, 256, 0, stream>>>(ea, cidx, row_ptr, N, easum);

    // ---------------- conv1: H=2, HC=128 ----------------
    k_xw<128, false><<<dim3(mt, 2), 256, 0, stream>>>(x, N, Wl1, bl1, Wr1, br1, xlb, xrb);
    k_ee<128><<<dim3(mt, 2), 256, 0, stream>>>(easum, N, We1, EEself);
    k_fused<2><<<et, 256, 0, stream>>>(xlb, xrb, ea, cidx, s_csr, d_csr, E, We1, att1, alpha);
    k_aggr<2, true, true><<<nblk, 256, 0, stream>>>(xlb, xrb, EEself, deg, att1, s_csr,
                                                    row_ptr, alpha, bias1, N, h1b);

    // ---------------- conv2: H=3, HC=192 ----------------
    k_xw<192, true><<<dim3(mt, 3), 256, 0, stream>>>(h1b, N, Wl2, bl2, Wr2, br2, xlb, xrb);
    k_ee<192><<<dim3(mt, 3), 256, 0, stream>>>(easum, N, We2, EEself);
    k_fused<3><<<et, 256, 0, stream>>>(xlb, xrb, ea, cidx, s_csr, d_csr, E, We2, att2, alpha);
    k_aggr<3, true, false><<<nblk, 256, 0, stream>>>(xlb, xrb, EEself, deg, att2, s_csr,
                                                     row_ptr, alpha, bias2, N, h2);

    k_pool<<<(N + 127) / 128, 192, 0, stream>>>(h2, batch, N, gp);
    k_mlp<<<1, 256, 0, stream>>>(gp, W1, c1, W2, c2, W3, c3, W4, c4, W5, c5, W6, c6,
                                 (float*)d_out);
}